// Round 3
// baseline (307.846 us; speedup 1.0000x reference)
//
#include <hip/hip_runtime.h>
#include <math.h>

// Problem constants: B=512, S=40, V_SC=7000, V_COMPO=1000, K=10
#define PB   512
#define PS   40
#define VSC  7000
#define VC   1000
#define PK   10
#define BK   (PB * PK)          // 5120   sc_labels slab
#define BKS  (PB * PK * PS)     // 204800 each seq slab

// Monotonic float->uint mapping (order-preserving, non-NaN)
__device__ __forceinline__ unsigned int ord_u32(float f) {
    unsigned int u = __float_as_uint(f);
    return (u & 0x80000000u) ? ~u : (u | 0x80000000u);
}
__device__ __forceinline__ float inv_ord(unsigned int ou) {
    return __uint_as_float((ou & 0x80000000u) ? (ou & 0x7fffffffu) : ~ou);
}

// ---------------------------------------------------------------------------
// Shared helpers for the compo path. CRITICAL: kernel 2 and kernel 4 must make
// bitwise-identical tie decisions, so both use these exact routines (same lane
// -> element mapping, same summation order, same butterfly order).
// Each lane holds 16 elements: element m=(j*4+e) is global index (j<<8)+(lane<<2)+e.
// ---------------------------------------------------------------------------
__device__ __forceinline__ void load_row16(const float* __restrict__ row, int lane, float* x) {
    const float4* r4 = (const float4*)row;
#pragma unroll
    for (int j = 0; j < 4; ++j) {
        int fi = (j << 6) + lane;
        float4 v;
        if (fi < VC / 4) v = r4[fi];
        else v = make_float4(-INFINITY, -INFINITY, -INFINITY, -INFINITY);
        x[j * 4 + 0] = v.x; x[j * 4 + 1] = v.y; x[j * 4 + 2] = v.z; x[j * 4 + 3] = v.w;
    }
}

__device__ __forceinline__ void wave_argmax(const float* x, int lane, float& xmax, int& amax) {
    float bv = -INFINITY; int bi = 0;
#pragma unroll
    for (int m = 0; m < 16; ++m) { if (x[m] > bv) { bv = x[m]; bi = m; } }
    int gidx = ((bi >> 2) << 8) + (lane << 2) + (bi & 3);
    unsigned long long key =
        ((unsigned long long)ord_u32(bv) << 32) |
        (unsigned long long)(0xFFFFFFFFu - (unsigned int)gidx);
#pragma unroll
    for (int off = 1; off < 64; off <<= 1) {
        unsigned long long o = __shfl_xor(key, off, 64);
        if (o > key) key = o;
    }
    xmax = inv_ord((unsigned int)(key >> 32));
    amax = (int)(0xFFFFFFFFu - (unsigned int)(key & 0xFFFFFFFFu));
}

// Deterministic f32 logsumexp pieces (order fixed: m ascending, butterfly 1..32).
// Pad elements are -INF -> exp = 0 exactly (adding 0.0f is a no-op in f32).
__device__ __forceinline__ float wave_sumexp(const float* x, float xmax) {
    float s = 0.0f;
#pragma unroll
    for (int m = 0; m < 16; ++m) s += expf(x[m] - xmax);
#pragma unroll
    for (int off = 1; off < 64; off <<= 1) s += __shfl_xor(s, off, 64);
    return s;   // identical across lanes (f32 add is commutative bitwise)
}

// ---------------------------------------------------------------------------
// Kernel 1: exact top-10 indices per row of (512,7000) f32 (raw-logit domain,
// jax.lax.top_k tie semantics). One 256-thread block per row.
// ---------------------------------------------------------------------------
__global__ __launch_bounds__(256) void topk_sc_kernel(const float* __restrict__ sc,
                                                      int* __restrict__ out) {
    const int b = blockIdx.x;
    const int t = threadIdx.x;
    const float* row = sc + (size_t)b * VSC;

    float v[28];
#pragma unroll
    for (int i = 0; i < 28; ++i) {
        int idx = t + (i << 8);
        v[i] = (idx < VSC) ? row[idx] : -INFINITY;
    }

    __shared__ unsigned long long wk[4];
    __shared__ int winner;

    for (int r = 0; r < PK; ++r) {
        float bv = -INFINITY; int bi = 0;
#pragma unroll
        for (int i = 0; i < 28; ++i) { if (v[i] > bv) { bv = v[i]; bi = i; } }
        int gidx = t + (bi << 8);
        unsigned long long key =
            ((unsigned long long)ord_u32(bv) << 32) |
            (unsigned long long)(0xFFFFFFFFu - (unsigned int)gidx);
#pragma unroll
        for (int off = 1; off < 64; off <<= 1) {
            unsigned long long o = __shfl_xor(key, off, 64);
            if (o > key) key = o;
        }
        if ((t & 63) == 0) wk[t >> 6] = key;
        __syncthreads();
        if (t == 0) {
            unsigned long long k0 = wk[0];
            if (wk[1] > k0) k0 = wk[1];
            if (wk[2] > k0) k0 = wk[2];
            if (wk[3] > k0) k0 = wk[3];
            int widx = (int)(0xFFFFFFFFu - (unsigned int)(k0 & 0xFFFFFFFFu));
            winner = widx;
            out[b * PK + r] = widx;
        }
        __syncthreads();
        int w = winner;
        if ((w & 255) == t) v[w >> 8] = -INFINITY;
    }
}

// ---------------------------------------------------------------------------
// Kernel 2: per (tensor,b,s) row of 1000: argmax -> j=0 slot of seq slab, and
// tie detection in log_softmax domain -> flag per (tensor,b) in ws.
// One wave per row, 4 rows per block.
// ---------------------------------------------------------------------------
__global__ __launch_bounds__(256) void argmax_compo_kernel(const float* __restrict__ lr,
                                                           const float* __restrict__ ul,
                                                           int* __restrict__ out,
                                                           int* __restrict__ tflag) {
    const int row  = blockIdx.x * 4 + (threadIdx.x >> 6);   // 0..40959
    const int lane = threadIdx.x & 63;
    const int tensor = (row >= PB * PS) ? 1 : 0;
    const int r2 = row - tensor * (PB * PS);
    const float* src = (tensor ? ul : lr) + (size_t)r2 * VC;

    float x[16];
    load_row16(src, lane, x);
    float xmax; int amax;
    wave_argmax(x, lane, xmax, amax);

    float se = wave_sumexp(x, xmax);
    float L = logf(se);
    float negL = 0.0f - L;
    int tcnt = 0;
#pragma unroll
    for (int m = 0; m < 16; ++m) {
        float scv = (x[m] - xmax) - L;   // bitwise == jax's shifted - log(sum(exp))
        tcnt += (scv == negL) ? 1 : 0;
    }
#pragma unroll
    for (int off = 1; off < 64; off <<= 1) tcnt += __shfl_xor(tcnt, off, 64);

    if (lane == 0) {
        int b = r2 / PS, s = r2 - (r2 / PS) * PS;
        out[BK + (size_t)tensor * BKS + (size_t)b * (PK * PS) + s] = amax;
        if (tcnt > 1) tflag[tensor * PB + b] = 1;   // rare; benign multi-store of 1
    }
}

// ---------------------------------------------------------------------------
// Kernel 3: replicate j=0 argmax across j=1..9 and build pred_results.
// ---------------------------------------------------------------------------
__global__ __launch_bounds__(256) void assemble_kernel(const int* __restrict__ struc,
                                                       int* __restrict__ out) {
    const int tid = blockIdx.x * 256 + threadIdx.x;
    if (tid >= BKS) return;
    const int b   = tid / (PK * PS);
    const int rem = tid - b * (PK * PS);
    const int j   = rem / PS;
    const int s   = rem - j * PS;

    int* lrslab = out + BK;
    int* ulslab = out + BK + BKS;
    const int lrv = lrslab[b * (PK * PS) + s];
    const int ulv = ulslab[b * (PK * PS) + s];

    if (j != 0) { lrslab[tid] = lrv; ulslab[tid] = ulv; }

    const int st = struc[b];
    int res = 0;
    if (st == 1)      res = lrv;
    else if (st == 2) res = ulv;
    else if (st == 0) res = (s == 0) ? out[b * PK + j] : 0;
    out[BK + 2 * BKS + tid] = res;
}

// ---------------------------------------------------------------------------
// Kernel 4 (rare path): for flagged (tensor,b), replay the exact beam
// recurrence. Per step i: t = multiplicity of max score (capped at 10),
// tokpos[0..t) = ascending indices achieving it; new_seq[j] = seq[j/t],
// new_seq[j][i] = tokpos[j%t]. Overwrites seq slab (+ pred_results if struc
// selects this tensor). One 64-thread block per (tensor,b); early-exit.
// ---------------------------------------------------------------------------
__global__ __launch_bounds__(64) void fix_ties_kernel(const float* __restrict__ lr,
                                                      const float* __restrict__ ul,
                                                      const int* __restrict__ struc,
                                                      const int* __restrict__ tflag,
                                                      int* __restrict__ out) {
    const int id = blockIdx.x;            // 0..1023
    if (tflag[id] == 0) return;           // uniform per block
    const int tensor = (id >= PB) ? 1 : 0;
    const int b = id - tensor * PB;
    const int lane = threadIdx.x;
    const float* src = (tensor ? ul : lr) + (size_t)b * PS * VC;

    __shared__ int seq[PK][PS];
    __shared__ int tokpos[PK];
    __shared__ int t_sh;

    for (int i = 0; i < PS; ++i) {
        float x[16];
        load_row16(src + (size_t)i * VC, lane, x);
        float xmax; int amax;
        wave_argmax(x, lane, xmax, amax);
        float se = wave_sumexp(x, xmax);
        float L = logf(se);
        float negL = 0.0f - L;

        // tie bits + parallel rank (global order = (j, lane, e) ascending)
        int rank_base = 0;
        unsigned long long below = (lane == 0) ? 0ull : ((~0ull) >> (64 - lane));
#pragma unroll
        for (int j = 0; j < 4; ++j) {
            int bit[4];
            unsigned long long Be[4];
#pragma unroll
            for (int e = 0; e < 4; ++e) {
                float scv = (x[j * 4 + e] - xmax) - L;
                bit[e] = (scv == negL) ? 1 : 0;
                Be[e] = __ballot(bit[e]);
            }
            int pre_lane = 0;
#pragma unroll
            for (int e = 0; e < 4; ++e) pre_lane += __popcll(Be[e] & below);
            int within = 0;
#pragma unroll
            for (int e = 0; e < 4; ++e) {
                if (bit[e]) {
                    int rk = rank_base + pre_lane + within;
                    if (rk < PK) tokpos[rk] = (j << 8) + (lane << 2) + e;
                    ++within;
                }
            }
            int grp = 0;
#pragma unroll
            for (int e = 0; e < 4; ++e) grp += __popcll(Be[e]);
            rank_base += grp;
        }
        if (lane == 0) t_sh = (rank_base < PK) ? rank_base : PK;
        __syncthreads();
        const int t = t_sh;

        int newrow[PS];
        if (lane < PK) {
            const int rsrc = lane / t;
#pragma unroll
            for (int q = 0; q < PS; ++q) newrow[q] = seq[rsrc][q];
        }
        __syncthreads();
        if (lane < PK) {
#pragma unroll
            for (int q = 0; q < PS; ++q) seq[lane][q] = newrow[q];
            seq[lane][i] = tokpos[lane % t];   // LDS runtime index: fine
        }
        __syncthreads();   // fences seq/tokpos for next iteration
    }

    int* slab = out + BK + (size_t)tensor * BKS + (size_t)b * (PK * PS);
    for (int q = lane; q < PK * PS; q += 64) slab[q] = seq[q / PS][q % PS];
    if (struc[b] == tensor + 1) {
        int* res = out + BK + 2 * BKS + (size_t)b * (PK * PS);
        for (int q = lane; q < PK * PS; q += 64) res[q] = seq[q / PS][q % PS];
    }
}

extern "C" void kernel_launch(void* const* d_in, const int* in_sizes, int n_in,
                              void* d_out, int out_size, void* d_ws, size_t ws_size,
                              hipStream_t stream) {
    const int*   struc = (const int*)d_in[0];
    const float* sc    = (const float*)d_in[1];
    const float* lr    = (const float*)d_in[2];
    const float* ul    = (const float*)d_in[3];
    int* out   = (int*)d_out;
    int* tflag = (int*)d_ws;    // 2*512 ints = 4 KB

    hipMemsetAsync(d_ws, 0, 2 * PB * sizeof(int), stream);   // capture-safe
    hipLaunchKernelGGL(topk_sc_kernel, dim3(PB), dim3(256), 0, stream, sc, out);
    hipLaunchKernelGGL(argmax_compo_kernel, dim3((2 * PB * PS) / 4), dim3(256), 0, stream,
                       lr, ul, out, tflag);
    hipLaunchKernelGGL(assemble_kernel, dim3((BKS + 255) / 256), dim3(256), 0, stream,
                       struc, out);
    hipLaunchKernelGGL(fix_ties_kernel, dim3(2 * PB), dim3(64), 0, stream,
                       lr, ul, struc, tflag, out);
}

// Round 4
// 251.398 us; speedup vs baseline: 1.2245x; 1.2245x over previous
//
#include <hip/hip_runtime.h>
#include <math.h>

// Problem constants: B=512, S=40, V_SC=7000, V_COMPO=1000, K=10
#define PB   512
#define PS   40
#define VSC  7000
#define VC   1000
#define PK   10
#define BK   (PB * PK)          // 5120   sc_labels slab
#define BKS  (PB * PK * PS)     // 204800 each seq slab
#define NROW (2 * PB * PS)      // 40960 compo rows (lr then ul)

// Monotonic float->uint mapping (order-preserving, non-NaN)
__device__ __forceinline__ unsigned int ord_u32(float f) {
    unsigned int u = __float_as_uint(f);
    return (u & 0x80000000u) ? ~u : (u | 0x80000000u);
}

// Each lane holds 16 elements: element m=(j*4+e) is global index (j<<8)+(lane<<2)+e.
__device__ __forceinline__ void load_row16(const float* __restrict__ row, int lane, float* x) {
    const float4* r4 = (const float4*)row;
#pragma unroll
    for (int j = 0; j < 4; ++j) {
        int fi = (j << 6) + lane;
        float4 v;
        if (fi < VC / 4) v = r4[fi];
        else v = make_float4(-INFINITY, -INFINITY, -INFINITY, -INFINITY);
        x[j * 4 + 0] = v.x; x[j * 4 + 1] = v.y; x[j * 4 + 2] = v.z; x[j * 4 + 3] = v.w;
    }
}

// max is exact -> any reduction order matches jax's row max bitwise
__device__ __forceinline__ float wave_max(const float* x) {
    float bv = -INFINITY;
#pragma unroll
    for (int m = 0; m < 16; ++m) bv = fmaxf(bv, x[m]);
#pragma unroll
    for (int off = 1; off < 64; off <<= 1) bv = fmaxf(bv, __shfl_xor(bv, off, 64));
    return bv;
}

// Deterministic f32 sumexp (order fixed: m ascending, butterfly 1..32).
// Pad elements are -INF -> exp = 0 exactly.
__device__ __forceinline__ float wave_sumexp(const float* x, float xmax) {
    float s = 0.0f;
#pragma unroll
    for (int m = 0; m < 16; ++m) s += expf(x[m] - xmax);
#pragma unroll
    for (int off = 1; off < 64; off <<= 1) s += __shfl_xor(s, off, 64);
    return s;
}

// ---------------------------------------------------------------------------
// Kernel 1: exact top-10 indices per row of (512,7000) f32 (raw-logit domain,
// jax.lax.top_k tie semantics). One 256-thread block per row.
// ---------------------------------------------------------------------------
__global__ __launch_bounds__(256) void topk_sc_kernel(const float* __restrict__ sc,
                                                      int* __restrict__ out) {
    const int b = blockIdx.x;
    const int t = threadIdx.x;
    const float* row = sc + (size_t)b * VSC;

    float v[28];
#pragma unroll
    for (int i = 0; i < 28; ++i) {
        int idx = t + (i << 8);
        v[i] = (idx < VSC) ? row[idx] : -INFINITY;
    }

    __shared__ unsigned long long wk[4];
    __shared__ int winner;

    for (int r = 0; r < PK; ++r) {
        float bv = -INFINITY; int bi = 0;
#pragma unroll
        for (int i = 0; i < 28; ++i) { if (v[i] > bv) { bv = v[i]; bi = i; } }
        int gidx = t + (bi << 8);
        unsigned long long key =
            ((unsigned long long)ord_u32(bv) << 32) |
            (unsigned long long)(0xFFFFFFFFu - (unsigned int)gidx);
#pragma unroll
        for (int off = 1; off < 64; off <<= 1) {
            unsigned long long o = __shfl_xor(key, off, 64);
            if (o > key) key = o;
        }
        if ((t & 63) == 0) wk[t >> 6] = key;
        __syncthreads();
        if (t == 0) {
            unsigned long long k0 = wk[0];
            if (wk[1] > k0) k0 = wk[1];
            if (wk[2] > k0) k0 = wk[2];
            if (wk[3] > k0) k0 = wk[3];
            int widx = (int)(0xFFFFFFFFu - (unsigned int)(k0 & 0xFFFFFFFFu));
            winner = widx;
            out[b * PK + r] = widx;
        }
        __syncthreads();
        int w = winner;
        if ((w & 255) == t) v[w >> 8] = -INFINITY;
    }
}

// ---------------------------------------------------------------------------
// Kernel 2: per compo row (tensor,b,s): in log_softmax score domain, find the
// multiplicity t of the max score (capped at 10) and the first min(t,10)
// positions achieving it (ascending index = jax.lax.top_k tie order).
// Store records to ws: ws_t[row] (ushort), ws_pos[row*10+c] (ushort).
// One wave per row, 4 rows per block. This is the single HBM-dominant pass.
// ---------------------------------------------------------------------------
__global__ __launch_bounds__(256) void rowrank_kernel(const float* __restrict__ lr,
                                                      const float* __restrict__ ul,
                                                      unsigned short* __restrict__ ws_t,
                                                      unsigned short* __restrict__ ws_pos) {
    const int row  = blockIdx.x * 4 + (threadIdx.x >> 6);   // 0..40959
    const int lane = threadIdx.x & 63;
    const int tensor = (row >= PB * PS) ? 1 : 0;
    const int r2 = row - tensor * (PB * PS);
    const float* src = (tensor ? ul : lr) + (size_t)r2 * VC;

    float x[16];
    load_row16(src, lane, x);
    const float xmax = wave_max(x);
    const float se = wave_sumexp(x, xmax);
    const float L = logf(se);
    const float negL = 0.0f - L;

    // tie bits + parallel rank (global order = (j, lane, e) ascending == index order)
    int rank_base = 0;
    unsigned long long below = (lane == 0) ? 0ull : ((~0ull) >> (64 - lane));
#pragma unroll
    for (int j = 0; j < 4; ++j) {
        int bit[4];
        unsigned long long Be[4];
#pragma unroll
        for (int e = 0; e < 4; ++e) {
            float scv = (x[j * 4 + e] - xmax) - L;   // bitwise == jax's log_softmax
            bit[e] = (scv == negL) ? 1 : 0;
            Be[e] = __ballot(bit[e]);
        }
        int pre_lane = 0;
#pragma unroll
        for (int e = 0; e < 4; ++e) pre_lane += __popcll(Be[e] & below);
        int within = 0;
#pragma unroll
        for (int e = 0; e < 4; ++e) {
            if (bit[e]) {
                int rk = rank_base + pre_lane + within;
                if (rk < PK) ws_pos[row * PK + rk] =
                    (unsigned short)((j << 8) + (lane << 2) + e);
                ++within;
            }
        }
        int grp = 0;
#pragma unroll
        for (int e = 0; e < 4; ++e) grp += __popcll(Be[e]);
        rank_base += grp;
    }
    if (lane == 0) ws_t[row] = (unsigned short)((rank_base < PK) ? rank_base : PK);
}

// ---------------------------------------------------------------------------
// Kernel 3: closed-form backward walk. Beam j's token at step i is
// tokpos[i][a_i % t_i] with a_{i-1} = a_i / t_i, a_{S-1} = j (beam scores are
// uniform forever, so comb's top-k reduces to this index arithmetic).
// One thread per (b, j): builds lr & ul seq rows and pred_results row.
// ws records are ~1 MB -> L2-resident. Replaces assemble + fix_ties.
// ---------------------------------------------------------------------------
__global__ __launch_bounds__(256) void build_kernel(const int* __restrict__ struc,
                                                    const unsigned short* __restrict__ ws_t,
                                                    const unsigned short* __restrict__ ws_pos,
                                                    int* __restrict__ out) {
    const int tid = blockIdx.x * 256 + threadIdx.x;   // 0..5119
    if (tid >= PB * PK) return;
    const int b = tid / PK;
    const int j = tid - b * PK;

    int* lrslab = out + BK + (size_t)b * (PK * PS) + (size_t)j * PS;
    int* ulslab = out + BK + BKS + (size_t)b * (PK * PS) + (size_t)j * PS;
    int* res    = out + BK + 2 * BKS + (size_t)b * (PK * PS) + (size_t)j * PS;
    const int st = struc[b];

#pragma unroll
    for (int tensor = 0; tensor < 2; ++tensor) {
        int* slab = tensor ? ulslab : lrslab;
        const int rbase = tensor * (PB * PS) + b * PS;
        int jc = j;
        for (int i = PS - 1; i >= 0; --i) {
            const int t = (int)ws_t[rbase + i];
            const int q = jc / t;
            const int c = jc - q * t;
            const int tok = (int)ws_pos[(rbase + i) * PK + c];
            slab[i] = tok;
            if (st == tensor + 1) res[i] = tok;
            jc = q;
        }
    }
    if (st == 0) {
        const int scv = out[b * PK + j];
        for (int i = 0; i < PS; ++i) res[i] = (i == 0) ? scv : 0;
    } else if (st != 1 && st != 2) {
        for (int i = 0; i < PS; ++i) res[i] = 0;
    }
}

extern "C" void kernel_launch(void* const* d_in, const int* in_sizes, int n_in,
                              void* d_out, int out_size, void* d_ws, size_t ws_size,
                              hipStream_t stream) {
    const int*   struc = (const int*)d_in[0];
    const float* sc    = (const float*)d_in[1];
    const float* lr    = (const float*)d_in[2];
    const float* ul    = (const float*)d_in[3];
    int* out = (int*)d_out;

    unsigned short* ws_t   = (unsigned short*)d_ws;              // 40960 * 2B
    unsigned short* ws_pos = ws_t + NROW;                        // 409600 * 2B (~900 KB total)

    hipLaunchKernelGGL(topk_sc_kernel, dim3(PB), dim3(256), 0, stream, sc, out);
    hipLaunchKernelGGL(rowrank_kernel, dim3(NROW / 4), dim3(256), 0, stream,
                       lr, ul, ws_t, ws_pos);
    hipLaunchKernelGGL(build_kernel, dim3((PB * PK + 255) / 256), dim3(256), 0, stream,
                       struc, ws_t, ws_pos, out);
}

// Round 9
// 248.035 us; speedup vs baseline: 1.2411x; 1.0136x over previous
//
#include <hip/hip_runtime.h>
#include <math.h>

// Problem constants: B=512, S=40, V_SC=7000, V_COMPO=1000, K=10
#define PB   512
#define PS   40
#define VSC  7000
#define VC   1000
#define PK   10
#define BK   (PB * PK)          // 5120   sc_labels slab
#define BKS  (PB * PK * PS)     // 204800 each seq slab
#define NROW (2 * PB * PS)      // 40960 compo rows (lr then ul)

// Any possible tie half-interval: u/2 = ulp(L)/2 <= 2^-22 (L <= log(1000) < 8).
#define NEAR_THR (-2.5e-7f)

// Monotonic float->uint mapping (order-preserving, non-NaN)
__device__ __forceinline__ unsigned int ord_u32(float f) {
    unsigned int u = __float_as_uint(f);
    return (u & 0x80000000u) ? ~u : (u | 0x80000000u);
}

// Each lane holds 16 elements: element m=(j*4+e) is global index (j<<8)+(lane<<2)+e.
__device__ __forceinline__ void load_row16(const float* __restrict__ row, int lane, float* x) {
    const float4* r4 = (const float4*)row;
#pragma unroll
    for (int j = 0; j < 4; ++j) {
        int fi = (j << 6) + lane;
        float4 v;
        if (fi < VC / 4) v = r4[fi];
        else v = make_float4(-INFINITY, -INFINITY, -INFINITY, -INFINITY);
        x[j * 4 + 0] = v.x; x[j * 4 + 1] = v.y; x[j * 4 + 2] = v.z; x[j * 4 + 3] = v.w;
    }
}

// max is exact -> reduction order free
__device__ __forceinline__ float wave_max(const float* x) {
    float bv = -INFINITY;
#pragma unroll
    for (int m = 0; m < 16; ++m) bv = fmaxf(bv, x[m]);
#pragma unroll
    for (int off = 1; off < 64; off <<= 1) bv = fmaxf(bv, __shfl_xor(bv, off, 64));
    return bv;
}

// Deterministic f32 sumexp (order fixed: m ascending, butterfly 1..32). Pad -INF -> +0.
__device__ __forceinline__ float wave_sumexp(const float* x, float xmax) {
    float s = 0.0f;
#pragma unroll
    for (int m = 0; m < 16; ++m) s += expf(x[m] - xmax);
#pragma unroll
    for (int off = 1; off < 64; off <<= 1) s += __shfl_xor(s, off, 64);
    return s;
}

// ---------------------------------------------------------------------------
// Kernel 1: exact top-10 indices per row of (512,7000) f32 (raw-logit domain,
// jax.lax.top_k tie semantics). One 256-thread block per row. (validated)
// ---------------------------------------------------------------------------
__global__ __launch_bounds__(256) void topk_sc_kernel(const float* __restrict__ sc,
                                                      int* __restrict__ out) {
    const int b = blockIdx.x;
    const int t = threadIdx.x;
    const float* row = sc + (size_t)b * VSC;

    float v[28];
#pragma unroll
    for (int i = 0; i < 28; ++i) {
        int idx = t + (i << 8);
        v[i] = (idx < VSC) ? row[idx] : -INFINITY;
    }

    __shared__ unsigned long long wk[4];
    __shared__ int winner;

    for (int r = 0; r < PK; ++r) {
        float bv = -INFINITY; int bi = 0;
#pragma unroll
        for (int i = 0; i < 28; ++i) { if (v[i] > bv) { bv = v[i]; bi = i; } }
        int gidx = t + (bi << 8);
        unsigned long long key =
            ((unsigned long long)ord_u32(bv) << 32) |
            (unsigned long long)(0xFFFFFFFFu - (unsigned int)gidx);
#pragma unroll
        for (int off = 1; off < 64; off <<= 1) {
            unsigned long long o = __shfl_xor(key, off, 64);
            if (o > key) key = o;
        }
        if ((t & 63) == 0) wk[t >> 6] = key;
        __syncthreads();
        if (t == 0) {
            unsigned long long k0 = wk[0];
            if (wk[1] > k0) k0 = wk[1];
            if (wk[2] > k0) k0 = wk[2];
            if (wk[3] > k0) k0 = wk[3];
            int widx = (int)(0xFFFFFFFFu - (unsigned int)(k0 & 0xFFFFFFFFu));
            winner = widx;
            out[b * PK + r] = widx;
        }
        __syncthreads();
        int w = winner;
        if ((w & 255) == t) v[w >> 8] = -INFINITY;
    }
}

// ---------------------------------------------------------------------------
// Kernel 2: per compo row: FAST PATH (no transcendentals) when at most one
// element is within any possible tie interval of the max; SLOW PATH (exact,
// bitwise-validated logsumexp + ballot-rank) otherwise (~1e-4 of rows).
// Tie set = {d in (-ulp(L)/2, 0]}, and ulp(L)/2 <= 2^-22 since L < 8, so
// counting d > -2.5e-7 gives a strict superset. count==1 -> t=1, tok=argmax.
// ---------------------------------------------------------------------------
__global__ __launch_bounds__(256) void rowrank_kernel(const float* __restrict__ lr,
                                                      const float* __restrict__ ul,
                                                      unsigned short* __restrict__ ws_t,
                                                      unsigned short* __restrict__ ws_pos) {
    const int row  = blockIdx.x * 4 + (threadIdx.x >> 6);   // 0..40959
    const int lane = threadIdx.x & 63;
    const int tensor = (row >= PB * PS) ? 1 : 0;
    const int r2 = row - tensor * (PB * PS);
    const float* src = (tensor ? ul : lr) + (size_t)r2 * VC;

    float x[16];
    load_row16(src, lane, x);
    const float xmax = wave_max(x);

    // near-max ballots (d <= 0 always; d > NEAR_THR is a superset of any tie set)
    unsigned long long Bn[16];
    int ncnt = 0;
#pragma unroll
    for (int m = 0; m < 16; ++m) {
        Bn[m] = __ballot((x[m] - xmax) > NEAR_THR);
    }
#pragma unroll
    for (int m = 0; m < 16; ++m) ncnt += __popcll(Bn[m]);   // wave-uniform

    if (ncnt == 1) {
        // tie-free row: the single near element is the max itself
        if (lane == 0) {
            int idx = 0;
#pragma unroll
            for (int m = 0; m < 16; ++m) {
                if (Bn[m]) idx = (((m >> 2) << 8)) + ((__ffsll((long long)Bn[m]) - 1) << 2) + (m & 3);
            }
            ws_t[row] = 1;
            ws_pos[row * PK] = (unsigned short)idx;
        }
        return;
    }

    // ---- slow path: exact score-domain ranking (bitwise-validated round-4 code)
    const float se = wave_sumexp(x, xmax);
    const float L = logf(se);
    const float negL = 0.0f - L;

    int rank_base = 0;
    unsigned long long below = (lane == 0) ? 0ull : ((~0ull) >> (64 - lane));
#pragma unroll
    for (int j = 0; j < 4; ++j) {
        int bit[4];
        unsigned long long Be[4];
#pragma unroll
        for (int e = 0; e < 4; ++e) {
            float scv = (x[j * 4 + e] - xmax) - L;   // bitwise == jax's log_softmax
            bit[e] = (scv == negL) ? 1 : 0;
            Be[e] = __ballot(bit[e]);
        }
        int pre_lane = 0;
#pragma unroll
        for (int e = 0; e < 4; ++e) pre_lane += __popcll(Be[e] & below);
        int within = 0;
#pragma unroll
        for (int e = 0; e < 4; ++e) {
            if (bit[e]) {
                int rk = rank_base + pre_lane + within;
                if (rk < PK) ws_pos[row * PK + rk] =
                    (unsigned short)((j << 8) + (lane << 2) + e);
                ++within;
            }
        }
        int grp = 0;
#pragma unroll
        for (int e = 0; e < 4; ++e) grp += __popcll(Be[e]);
        rank_base += grp;
    }
    if (lane == 0) ws_t[row] = (unsigned short)((rank_base < PK) ? rank_base : PK);
}

// ---------------------------------------------------------------------------
// Kernel 3: closed-form backward walk. Beam j's token at step i is
// tokpos[i][a_i % t_i] with a_{i-1} = a_i / t_i, a_{S-1} = j.
// One thread per (b, j); ws records are ~1 MB -> L2/L3-resident.
// ---------------------------------------------------------------------------
__global__ __launch_bounds__(256) void build_kernel(const int* __restrict__ struc,
                                                    const unsigned short* __restrict__ ws_t,
                                                    const unsigned short* __restrict__ ws_pos,
                                                    int* __restrict__ out) {
    const int tid = blockIdx.x * 256 + threadIdx.x;   // 0..5119
    if (tid >= PB * PK) return;
    const int b = tid / PK;
    const int j = tid - b * PK;

    int* lrslab = out + BK + (size_t)b * (PK * PS) + (size_t)j * PS;
    int* ulslab = out + BK + BKS + (size_t)b * (PK * PS) + (size_t)j * PS;
    int* res    = out + BK + 2 * BKS + (size_t)b * (PK * PS) + (size_t)j * PS;
    const int st = struc[b];

#pragma unroll
    for (int tensor = 0; tensor < 2; ++tensor) {
        int* slab = tensor ? ulslab : lrslab;
        const int rbase = tensor * (PB * PS) + b * PS;
        int jc = j;
        for (int i = PS - 1; i >= 0; --i) {
            const int t = (int)ws_t[rbase + i];
            int q, c;
            if (t == 1) { q = jc; c = 0; }           // common case: skip u32 divide
            else        { q = jc / t; c = jc - q * t; }
            const int tok = (int)ws_pos[(rbase + i) * PK + c];
            slab[i] = tok;
            if (st == tensor + 1) res[i] = tok;
            jc = q;
        }
    }
    if (st == 0) {
        const int scv = out[b * PK + j];
        for (int i = 0; i < PS; ++i) res[i] = (i == 0) ? scv : 0;
    } else if (st != 1 && st != 2) {
        for (int i = 0; i < PS; ++i) res[i] = 0;
    }
}

extern "C" void kernel_launch(void* const* d_in, const int* in_sizes, int n_in,
                              void* d_out, int out_size, void* d_ws, size_t ws_size,
                              hipStream_t stream) {
    const int*   struc = (const int*)d_in[0];
    const float* sc    = (const float*)d_in[1];
    const float* lr    = (const float*)d_in[2];
    const float* ul    = (const float*)d_in[3];
    int* out = (int*)d_out;

    unsigned short* ws_t   = (unsigned short*)d_ws;   // 40960 * 2B
    unsigned short* ws_pos = ws_t + NROW;             // 409600 * 2B (~900 KB total)

    hipLaunchKernelGGL(topk_sc_kernel, dim3(PB), dim3(256), 0, stream, sc, out);
    hipLaunchKernelGGL(rowrank_kernel, dim3(NROW / 4), dim3(256), 0, stream,
                       lr, ul, ws_t, ws_pos);
    hipLaunchKernelGGL(build_kernel, dim3((PB * PK + 255) / 256), dim3(256), 0, stream,
                       struc, ws_t, ws_pos, out);
}